// Round 1
// baseline (1715.770 us; speedup 1.0000x reference)
//
#include <hip/hip_runtime.h>
#include <cmath>

// PropConv: K=10 hop gated propagation on a fixed graph + output MLP.
// Strategy: build dst-CSR once per call (hist+scan+scatter), fold
// w[e]*src_norm[src[e]] into one per-edge coefficient, then each hop is a
// pure gather-SpMM (1 wave per dst node, float2 per lane). Working set
// (~77MB) is L3-resident, so hops run at cache BW.

#define NNODES 50000
#define NEDGES 1600000
#define DD 128
#define KHOPS 10
#define ALPHA 0.1f

__global__ void deg_kernel(const int* __restrict__ src, const int* __restrict__ dst,
                           int* __restrict__ outcnt, int* __restrict__ incnt, int E) {
    int e = blockIdx.x * blockDim.x + threadIdx.x;
    if (e < E) {
        atomicAdd(&outcnt[src[e]], 1);
        atomicAdd(&incnt[dst[e]], 1);
    }
}

// src/dst norms + 8-entry gate table (gate MLP has only 8 distinct inputs).
__global__ void norm_gate_kernel(const int* __restrict__ outcnt, const int* __restrict__ incnt,
                                 float* __restrict__ srcn, float* __restrict__ dstn,
                                 const float* __restrict__ emb, const float* __restrict__ We1,
                                 const float* __restrict__ be1, const float* __restrict__ We2,
                                 const float* __restrict__ be2, float* __restrict__ gate, int N) {
    int n = blockIdx.x * blockDim.x + threadIdx.x;
    if (n < N) {
        int oc = outcnt[n] < 1 ? 1 : outcnt[n];
        int ic = incnt[n] < 1 ? 1 : incnt[n];
        srcn[n] = 1.0f / sqrtf((float)oc);
        dstn[n] = 1.0f / sqrtf((float)ic);
    }
    if (blockIdx.x == 0 && threadIdx.x < 8) {
        int t = threadIdx.x;
        float acc2 = 0.0f;
        for (int j = 0; j < 32; j++) {
            float a = be1[j];
            for (int k = 0; k < DD; k++) a += emb[t * DD + k] * We1[k * 32 + j];
            float g = 0.5f * a * (1.0f + erff(a * 0.70710678118654752f));  // exact GELU
            acc2 += g * We2[j];
        }
        acc2 += be2[0];
        gate[t] = 1.0f + 1.0f / (1.0f + expf(-acc2));   // 1 + sigmoid
    }
}

// Single-block exclusive scan of in-degree counts -> row_ptr.
__global__ __launch_bounds__(1024) void scan_kernel(const int* __restrict__ cnt,
                                                    int* __restrict__ row_ptr, int N, int E) {
    __shared__ int part[1024];
    int t = threadIdx.x;
    int chunk = (N + 1023) / 1024;
    int beg = t * chunk; if (beg > N) beg = N;
    int end = beg + chunk; if (end > N) end = N;
    int s = 0;
    for (int i = beg; i < end; i++) s += cnt[i];
    part[t] = s;
    __syncthreads();
    for (int off = 1; off < 1024; off <<= 1) {
        int v = 0;
        if (t >= off) v = part[t - off];
        __syncthreads();
        if (t >= off) part[t] += v;
        __syncthreads();
    }
    int excl = (t == 0) ? 0 : part[t - 1];
    for (int i = beg; i < end; i++) { row_ptr[i] = excl; excl += cnt[i]; }
    if (t == 0) row_ptr[N] = E;
}

// Bucket edges by dst; c[e] = gate[etype] * src_norm[src] (hop-invariant).
__global__ void scatter_kernel(const int* __restrict__ src, const int* __restrict__ dst,
                               const int* __restrict__ ef, const float* __restrict__ srcn,
                               const float* __restrict__ gate, const int* __restrict__ row_ptr,
                               int* __restrict__ cursor, int* __restrict__ col,
                               float* __restrict__ cval, int E) {
    int e = blockIdx.x * blockDim.x + threadIdx.x;
    if (e >= E) return;
    int d = dst[e];
    int pos = row_ptr[d] + atomicAdd(&cursor[d], 1);
    int s = src[e];
    col[pos] = s;
    cval[pos] = gate[ef[e]] * srcn[s];
}

// One wave per dst node; lane holds float2 of the 512B row. Edge (src,c)
// pairs loaded coalesced in chunks of 64, broadcast via __shfl.
__global__ __launch_bounds__(256) void hop_kernel(const float* __restrict__ h_in,
                                                  const float* __restrict__ feat0,
                                                  const float* __restrict__ dstn,
                                                  const int* __restrict__ row_ptr,
                                                  const int* __restrict__ col,
                                                  const float* __restrict__ cval,
                                                  float* __restrict__ h_out, int N) {
    int wave = threadIdx.x >> 6;
    int lane = threadIdx.x & 63;
    int node = blockIdx.x * 4 + wave;
    if (node >= N) return;
    int beg = row_ptr[node], end = row_ptr[node + 1];
    float ax = 0.0f, ay = 0.0f;
    for (int base = beg; base < end; base += 64) {
        int n = end - base; if (n > 64) n = 64;
        int s = 0; float c = 0.0f;
        if (lane < n) { s = col[base + lane]; c = cval[base + lane]; }
        for (int j = 0; j < n; j++) {
            int sj = __shfl(s, j, 64);
            float cj = __shfl(c, j, 64);
            const float2 hv = *(const float2*)(h_in + (size_t)sj * DD + lane * 2);
            ax += cj * hv.x;
            ay += cj * hv.y;
        }
    }
    float dn = dstn[node] * (1.0f - ALPHA);
    const float2 fv = *(const float2*)(feat0 + (size_t)node * DD + lane * 2);
    float2 o;
    o.x = dn * ax + ALPHA * fv.x;
    o.y = dn * ay + ALPHA * fv.y;
    *(float2*)(h_out + (size_t)node * DD + lane * 2) = o;
}

// [N,128]@[128,128] GEMM, f32 vector ALU (no f32 MFMA on CDNA4).
// 32-row tile in LDS + 64-row W chunk in LDS (48KB total -> 3 blocks/CU).
// Thread computes 4 rows x 4 cols.
__global__ __launch_bounds__(256) void mlp_kernel(const float* __restrict__ in,
                                                  const float* __restrict__ W,
                                                  const float* __restrict__ bias,
                                                  float* __restrict__ out, int N, int do_gelu) {
    __shared__ float Wt[64 * DD];    // 32 KB
    __shared__ float ins[32 * DD];   // 16 KB
    int tid = threadIdx.x;
    int row0 = blockIdx.x * 32;
    int nrows = N - row0; if (nrows > 32) nrows = 32;
    for (int i = tid; i < nrows * DD; i += 256) ins[i] = in[(size_t)row0 * DD + i];

    int jc = (tid & 31) * 4;
    int rr = (tid >> 5) * 4;
    float acc[4][4];
#pragma unroll
    for (int r = 0; r < 4; r++)
#pragma unroll
        for (int c = 0; c < 4; c++) acc[r][c] = 0.0f;

    for (int k0 = 0; k0 < DD; k0 += 64) {
        __syncthreads();
        for (int i = tid; i < 64 * DD; i += 256) Wt[i] = W[(size_t)k0 * DD + i];
        __syncthreads();
#pragma unroll 4
        for (int k = 0; k < 64; k++) {
            float4 wv = *(const float4*)&Wt[k * DD + jc];
#pragma unroll
            for (int r = 0; r < 4; r++) {
                float a = ins[(rr + r) * DD + (k0 + k)];
                acc[r][0] += a * wv.x;
                acc[r][1] += a * wv.y;
                acc[r][2] += a * wv.z;
                acc[r][3] += a * wv.w;
            }
        }
    }
    float4 bv = *(const float4*)&bias[jc];
#pragma unroll
    for (int r = 0; r < 4; r++) {
        int row = row0 + rr + r;
        if (row >= N) continue;
        float4 v;
        v.x = acc[r][0] + bv.x; v.y = acc[r][1] + bv.y;
        v.z = acc[r][2] + bv.z; v.w = acc[r][3] + bv.w;
        if (do_gelu) {
            v.x = 0.5f * v.x * (1.0f + erff(v.x * 0.70710678118654752f));
            v.y = 0.5f * v.y * (1.0f + erff(v.y * 0.70710678118654752f));
            v.z = 0.5f * v.z * (1.0f + erff(v.z * 0.70710678118654752f));
            v.w = 0.5f * v.w * (1.0f + erff(v.w * 0.70710678118654752f));
        }
        *(float4*)(out + (size_t)row * DD + jc) = v;
    }
}

extern "C" void kernel_launch(void* const* d_in, const int* in_sizes, int n_in,
                              void* d_out, int out_size, void* d_ws, size_t ws_size,
                              hipStream_t stream) {
    const float* feat = (const float*)d_in[0];
    const int*   e_feat = (const int*)d_in[1];
    const int*   src = (const int*)d_in[2];
    const int*   dst = (const int*)d_in[3];
    const float* emb = (const float*)d_in[4];
    const float* We1 = (const float*)d_in[5];
    const float* be1 = (const float*)d_in[6];
    const float* We2 = (const float*)d_in[7];
    const float* be2 = (const float*)d_in[8];
    const float* W1  = (const float*)d_in[9];
    const float* b1  = (const float*)d_in[10];
    const float* W2  = (const float*)d_in[11];
    const float* b2  = (const float*)d_in[12];
    float* out = (float*)d_out;

    const int N = NNODES, E = NEDGES;
    char* ws = (char*)d_ws;
    size_t off = 0;
    float* ha = (float*)(ws + off);      off += (size_t)N * DD * 4;   // 25.6 MB
    float* hb = (float*)(ws + off);      off += (size_t)N * DD * 4;   // 25.6 MB
    int*   col = (int*)(ws + off);       off += (size_t)E * 4;        // 6.4 MB
    float* cval = (float*)(ws + off);    off += (size_t)E * 4;        // 6.4 MB
    int*   row_ptr = (int*)(ws + off);   off += (size_t)(N + 1) * 4;
    int*   cnts = (int*)(ws + off);      off += (size_t)3 * N * 4;    // outcnt|incnt|cursor
    float* srcn = (float*)(ws + off);    off += (size_t)N * 4;
    float* dstn = (float*)(ws + off);    off += (size_t)N * 4;
    float* gate = (float*)(ws + off);    off += 64;
    int* outcnt = cnts;
    int* incnt  = cnts + N;
    int* cursor = cnts + 2 * N;

    hipMemsetAsync(cnts, 0, (size_t)3 * N * 4, stream);
    deg_kernel<<<E / 256, 256, 0, stream>>>(src, dst, outcnt, incnt, E);
    norm_gate_kernel<<<(N + 255) / 256, 256, 0, stream>>>(outcnt, incnt, srcn, dstn,
                                                          emb, We1, be1, We2, be2, gate, N);
    scan_kernel<<<1, 1024, 0, stream>>>(incnt, row_ptr, N, E);
    scatter_kernel<<<E / 256, 256, 0, stream>>>(src, dst, e_feat, srcn, gate, row_ptr,
                                                cursor, col, cval, E);

    const float* hin = feat;
    float* hout = ha;
    for (int k = 0; k < KHOPS; k++) {
        hop_kernel<<<(N + 3) / 4, 256, 0, stream>>>(hin, feat, dstn, row_ptr, col, cval, hout, N);
        hin = hout;
        hout = (hout == ha) ? hb : ha;
    }
    // hin = final h (hb); hout = free buffer (ha) -> reuse as hidden.
    float* hidden = hout;
    mlp_kernel<<<(N + 31) / 32, 256, 0, stream>>>(hin, W1, b1, hidden, N, 1);
    mlp_kernel<<<(N + 31) / 32, 256, 0, stream>>>(hidden, W2, b2, out, N, 0);
}

// Round 2
// 1596.472 us; speedup vs baseline: 1.0747x; 1.0747x over previous
//
#include <hip/hip_runtime.h>
#include <cmath>

// PropConv: K=10 hop gated propagation on a fixed graph + output MLP.
// R2: hop kernel restructured for memory-level parallelism — half-wave
// (32 lanes) per dst node, float4 per lane (covers 512B row), inner loop
// unrolled x4 so 4 independent 16B gathers are in flight per lane.
// Scatter now writes (src,coef) as one int2 (halves dirtied cachelines).

#define NNODES 50000
#define NEDGES 1600000
#define DD 128
#define KHOPS 10
#define ALPHA 0.1f

__global__ void deg_kernel(const int* __restrict__ src, const int* __restrict__ dst,
                           int* __restrict__ outcnt, int* __restrict__ incnt, int E) {
    int e = blockIdx.x * blockDim.x + threadIdx.x;
    if (e < E) {
        atomicAdd(&outcnt[src[e]], 1);
        atomicAdd(&incnt[dst[e]], 1);
    }
}

// src/dst norms + 8-entry gate table (gate MLP has only 8 distinct inputs).
__global__ void norm_gate_kernel(const int* __restrict__ outcnt, const int* __restrict__ incnt,
                                 float* __restrict__ srcn, float* __restrict__ dstn,
                                 const float* __restrict__ emb, const float* __restrict__ We1,
                                 const float* __restrict__ be1, const float* __restrict__ We2,
                                 const float* __restrict__ be2, float* __restrict__ gate, int N) {
    int n = blockIdx.x * blockDim.x + threadIdx.x;
    if (n < N) {
        int oc = outcnt[n] < 1 ? 1 : outcnt[n];
        int ic = incnt[n] < 1 ? 1 : incnt[n];
        srcn[n] = 1.0f / sqrtf((float)oc);
        dstn[n] = 1.0f / sqrtf((float)ic);
    }
    if (blockIdx.x == 0 && threadIdx.x < 8) {
        int t = threadIdx.x;
        float acc2 = 0.0f;
        for (int j = 0; j < 32; j++) {
            float a = be1[j];
            for (int k = 0; k < DD; k++) a += emb[t * DD + k] * We1[k * 32 + j];
            float g = 0.5f * a * (1.0f + erff(a * 0.70710678118654752f));  // exact GELU
            acc2 += g * We2[j];
        }
        acc2 += be2[0];
        gate[t] = 1.0f + 1.0f / (1.0f + expf(-acc2));   // 1 + sigmoid
    }
}

// Single-block exclusive scan of in-degree counts -> row_ptr.
__global__ __launch_bounds__(1024) void scan_kernel(const int* __restrict__ cnt,
                                                    int* __restrict__ row_ptr, int N, int E) {
    __shared__ int part[1024];
    int t = threadIdx.x;
    int chunk = (N + 1023) / 1024;
    int beg = t * chunk; if (beg > N) beg = N;
    int end = beg + chunk; if (end > N) end = N;
    int s = 0;
    for (int i = beg; i < end; i++) s += cnt[i];
    part[t] = s;
    __syncthreads();
    for (int off = 1; off < 1024; off <<= 1) {
        int v = 0;
        if (t >= off) v = part[t - off];
        __syncthreads();
        if (t >= off) part[t] += v;
        __syncthreads();
    }
    int excl = (t == 0) ? 0 : part[t - 1];
    for (int i = beg; i < end; i++) { row_ptr[i] = excl; excl += cnt[i]; }
    if (t == 0) row_ptr[N] = E;
}

// Bucket edges by dst; edge payload = (src, gate[etype]*src_norm[src]) as int2
// so the random scatter dirties one cacheline per edge, not two.
__global__ void scatter_kernel(const int* __restrict__ src, const int* __restrict__ dst,
                               const int* __restrict__ ef, const float* __restrict__ srcn,
                               const float* __restrict__ gate, const int* __restrict__ row_ptr,
                               int* __restrict__ cursor, int2* __restrict__ edges, int E) {
    int e = blockIdx.x * blockDim.x + threadIdx.x;
    if (e >= E) return;
    int d = dst[e];
    int pos = row_ptr[d] + atomicAdd(&cursor[d], 1);
    int s = src[e];
    int2 p;
    p.x = s;
    p.y = __float_as_int(gate[ef[e]] * srcn[s]);
    edges[pos] = p;
}

// Half-wave (32 lanes) per dst node; lane holds float4 of the 512B row.
// Edge (src,c) pairs loaded coalesced in chunks of 32, broadcast via __shfl
// (width 32 = segment). Inner loop unrolled x4 -> 4 gathers in flight/lane.
__global__ __launch_bounds__(256) void hop_kernel(const float* __restrict__ h_in,
                                                  const float* __restrict__ feat0,
                                                  const float* __restrict__ dstn,
                                                  const int* __restrict__ row_ptr,
                                                  const int2* __restrict__ edges,
                                                  float* __restrict__ h_out, int N) {
    int half = threadIdx.x >> 5;     // 0..7
    int lane = threadIdx.x & 31;
    int node = blockIdx.x * 8 + half;
    if (node >= N) return;
    int beg = row_ptr[node], end = row_ptr[node + 1];
    int col = lane * 4;
    float ax = 0.f, ay = 0.f, az = 0.f, aw = 0.f;
    for (int base = beg; base < end; base += 32) {
        int n = end - base; if (n > 32) n = 32;
        int sv = 0; float cv = 0.f;
        if (lane < n) {
            int2 p = edges[base + lane];
            sv = p.x;
            cv = __int_as_float(p.y);
        }
        int j = 0;
        for (; j + 4 <= n; j += 4) {
            int   s0 = __shfl(sv, j + 0, 32); float c0 = __shfl(cv, j + 0, 32);
            int   s1 = __shfl(sv, j + 1, 32); float c1 = __shfl(cv, j + 1, 32);
            int   s2 = __shfl(sv, j + 2, 32); float c2 = __shfl(cv, j + 2, 32);
            int   s3 = __shfl(sv, j + 3, 32); float c3 = __shfl(cv, j + 3, 32);
            float4 v0 = *(const float4*)(h_in + (size_t)s0 * DD + col);
            float4 v1 = *(const float4*)(h_in + (size_t)s1 * DD + col);
            float4 v2 = *(const float4*)(h_in + (size_t)s2 * DD + col);
            float4 v3 = *(const float4*)(h_in + (size_t)s3 * DD + col);
            ax += c0 * v0.x; ay += c0 * v0.y; az += c0 * v0.z; aw += c0 * v0.w;
            ax += c1 * v1.x; ay += c1 * v1.y; az += c1 * v1.z; aw += c1 * v1.w;
            ax += c2 * v2.x; ay += c2 * v2.y; az += c2 * v2.z; aw += c2 * v2.w;
            ax += c3 * v3.x; ay += c3 * v3.y; az += c3 * v3.z; aw += c3 * v3.w;
        }
        for (; j < n; j++) {
            int   sj = __shfl(sv, j, 32);
            float cj = __shfl(cv, j, 32);
            float4 v = *(const float4*)(h_in + (size_t)sj * DD + col);
            ax += cj * v.x; ay += cj * v.y; az += cj * v.z; aw += cj * v.w;
        }
    }
    float dn = dstn[node] * (1.0f - ALPHA);
    float4 fv = *(const float4*)(feat0 + (size_t)node * DD + col);
    float4 o;
    o.x = dn * ax + ALPHA * fv.x;
    o.y = dn * ay + ALPHA * fv.y;
    o.z = dn * az + ALPHA * fv.z;
    o.w = dn * aw + ALPHA * fv.w;
    *(float4*)(h_out + (size_t)node * DD + col) = o;
}

// [N,128]@[128,128] GEMM, f32 vector ALU (no f32 MFMA on CDNA4).
// 32-row tile in LDS + 64-row W chunk in LDS (48KB total -> 3 blocks/CU).
// Thread computes 4 rows x 4 cols.
__global__ __launch_bounds__(256) void mlp_kernel(const float* __restrict__ in,
                                                  const float* __restrict__ W,
                                                  const float* __restrict__ bias,
                                                  float* __restrict__ out, int N, int do_gelu) {
    __shared__ float Wt[64 * DD];    // 32 KB
    __shared__ float ins[32 * DD];   // 16 KB
    int tid = threadIdx.x;
    int row0 = blockIdx.x * 32;
    int nrows = N - row0; if (nrows > 32) nrows = 32;
    for (int i = tid; i < nrows * DD; i += 256) ins[i] = in[(size_t)row0 * DD + i];

    int jc = (tid & 31) * 4;
    int rr = (tid >> 5) * 4;
    float acc[4][4];
#pragma unroll
    for (int r = 0; r < 4; r++)
#pragma unroll
        for (int c = 0; c < 4; c++) acc[r][c] = 0.0f;

    for (int k0 = 0; k0 < DD; k0 += 64) {
        __syncthreads();
        for (int i = tid; i < 64 * DD; i += 256) Wt[i] = W[(size_t)k0 * DD + i];
        __syncthreads();
#pragma unroll 4
        for (int k = 0; k < 64; k++) {
            float4 wv = *(const float4*)&Wt[k * DD + jc];
#pragma unroll
            for (int r = 0; r < 4; r++) {
                float a = ins[(rr + r) * DD + (k0 + k)];
                acc[r][0] += a * wv.x;
                acc[r][1] += a * wv.y;
                acc[r][2] += a * wv.z;
                acc[r][3] += a * wv.w;
            }
        }
    }
    float4 bv = *(const float4*)&bias[jc];
#pragma unroll
    for (int r = 0; r < 4; r++) {
        int row = row0 + rr + r;
        if (row >= N) continue;
        float4 v;
        v.x = acc[r][0] + bv.x; v.y = acc[r][1] + bv.y;
        v.z = acc[r][2] + bv.z; v.w = acc[r][3] + bv.w;
        if (do_gelu) {
            v.x = 0.5f * v.x * (1.0f + erff(v.x * 0.70710678118654752f));
            v.y = 0.5f * v.y * (1.0f + erff(v.y * 0.70710678118654752f));
            v.z = 0.5f * v.z * (1.0f + erff(v.z * 0.70710678118654752f));
            v.w = 0.5f * v.w * (1.0f + erff(v.w * 0.70710678118654752f));
        }
        *(float4*)(out + (size_t)row * DD + jc) = v;
    }
}

extern "C" void kernel_launch(void* const* d_in, const int* in_sizes, int n_in,
                              void* d_out, int out_size, void* d_ws, size_t ws_size,
                              hipStream_t stream) {
    const float* feat = (const float*)d_in[0];
    const int*   e_feat = (const int*)d_in[1];
    const int*   src = (const int*)d_in[2];
    const int*   dst = (const int*)d_in[3];
    const float* emb = (const float*)d_in[4];
    const float* We1 = (const float*)d_in[5];
    const float* be1 = (const float*)d_in[6];
    const float* We2 = (const float*)d_in[7];
    const float* be2 = (const float*)d_in[8];
    const float* W1  = (const float*)d_in[9];
    const float* b1  = (const float*)d_in[10];
    const float* W2  = (const float*)d_in[11];
    const float* b2  = (const float*)d_in[12];
    float* out = (float*)d_out;

    const int N = NNODES, E = NEDGES;
    char* ws = (char*)d_ws;
    size_t off = 0;
    float* ha = (float*)(ws + off);      off += (size_t)N * DD * 4;   // 25.6 MB
    float* hb = (float*)(ws + off);      off += (size_t)N * DD * 4;   // 25.6 MB
    int2*  edges = (int2*)(ws + off);    off += (size_t)E * 8;        // 12.8 MB
    int*   row_ptr = (int*)(ws + off);   off += (size_t)(N + 1) * 4;
    int*   cnts = (int*)(ws + off);      off += (size_t)3 * N * 4;    // outcnt|incnt|cursor
    float* srcn = (float*)(ws + off);    off += (size_t)N * 4;
    float* dstn = (float*)(ws + off);    off += (size_t)N * 4;
    float* gate = (float*)(ws + off);    off += 64;
    int* outcnt = cnts;
    int* incnt  = cnts + N;
    int* cursor = cnts + 2 * N;

    hipMemsetAsync(cnts, 0, (size_t)3 * N * 4, stream);
    deg_kernel<<<E / 256, 256, 0, stream>>>(src, dst, outcnt, incnt, E);
    norm_gate_kernel<<<(N + 255) / 256, 256, 0, stream>>>(outcnt, incnt, srcn, dstn,
                                                          emb, We1, be1, We2, be2, gate, N);
    scan_kernel<<<1, 1024, 0, stream>>>(incnt, row_ptr, N, E);
    scatter_kernel<<<E / 256, 256, 0, stream>>>(src, dst, e_feat, srcn, gate, row_ptr,
                                                cursor, edges, E);

    const float* hin = feat;
    float* hout = ha;
    for (int k = 0; k < KHOPS; k++) {
        hop_kernel<<<(N + 7) / 8, 256, 0, stream>>>(hin, feat, dstn, row_ptr, edges, hout, N);
        hin = hout;
        hout = (hout == ha) ? hb : ha;
    }
    // hin = final h (hb); hout = free buffer (ha) -> reuse as hidden.
    float* hidden = hout;
    mlp_kernel<<<(N + 31) / 32, 256, 0, stream>>>(hin, W1, b1, hidden, N, 1);
    mlp_kernel<<<(N + 31) / 32, 256, 0, stream>>>(hidden, W2, b2, out, N, 0);
}